// Round 8
// baseline (195.652 us; speedup 1.0000x reference)
//
#include <hip/hip_runtime.h>

typedef unsigned int u32;
typedef unsigned short u16;
typedef unsigned char u8;
typedef __attribute__((ext_vector_type(8))) short bf16x8;
typedef __attribute__((ext_vector_type(4))) float f32x4;

#define JAX_PARTITIONABLE 1
#define FLAG_DELTA 5e-4f
#define FLAG_CAP 262144u

// ---------- Threefry-2x32, 20 rounds (matches jax._src.prng.threefry2x32) ----
__host__ __device__ static inline void tf2x32(u32 k0, u32 k1, u32 x0, u32 x1,
                                              u32* o0, u32* o1)
{
  const u32 ks2 = k0 ^ k1 ^ 0x1BD11BDAu;
#define TF_R(v, r) (((v) << (r)) | ((v) >> (32 - (r))))
#define TF_RND(r) do { x0 += x1; x1 = TF_R(x1, r); x1 ^= x0; } while (0);
  x0 += k0; x1 += k1;
  TF_RND(13) TF_RND(15) TF_RND(26) TF_RND(6)
  x0 += k1;  x1 += ks2 + 1u;
  TF_RND(17) TF_RND(29) TF_RND(16) TF_RND(24)
  x0 += ks2; x1 += k0 + 2u;
  TF_RND(13) TF_RND(15) TF_RND(26) TF_RND(6)
  x0 += k0;  x1 += k1 + 3u;
  TF_RND(17) TF_RND(29) TF_RND(16) TF_RND(24)
  x0 += k1;  x1 += ks2 + 4u;
  TF_RND(13) TF_RND(15) TF_RND(26) TF_RND(6)
  x0 += ks2; x1 += k0 + 5u;
  *o0 = x0; *o1 = x1;
#undef TF_RND
#undef TF_R
}

__device__ static inline u16 f2bf(float f) {
  u32 u = __float_as_uint(f);
  return (u16)((u + 0x7FFFu + ((u >> 16) & 1u)) >> 16);
}
__device__ static inline float bf2f(u16 b) {
  return __uint_as_float(((u32)b) << 16);
}

// ---------- K0: x = q @ W_in (exact ascending-d chain), 4 b per block -------
// 4 waves/block, wave w owns b = blockIdx*4+w; q rows staged (float4); win
// column stream double-buffered 64-deep, shared across waves via L1.
// Chain order bit-identical to the R2-verified version.
__global__ __launch_bounds__(256) void k_gate(
    const float* __restrict__ q, const float* __restrict__ win,
    const float* __restrict__ gbias, const float* __restrict__ temp,
    const float* __restrict__ gk, float* __restrict__ rates,
    float* __restrict__ gateo, u32* __restrict__ fcnt)
{
  const int tid = threadIdx.x;
  if (blockIdx.x == 0 && tid == 0) fcnt[0] = 0;
  __shared__ float qs[4][1024];
  const int b4 = blockIdx.x * 4;
#pragma unroll
  for (int r = 0; r < 4; ++r) {
    const float4 qv = *(const float4*)(q + (size_t)(b4 + r) * 1024 + tid * 4);
    *(float4*)(&qs[r][tid * 4]) = qv;
  }
  __syncthreads();

  const int w = tid >> 6, j = tid & 63;
  const int b = b4 + w;
  const float* __restrict__ wc = win + j;
  float bufA[64], bufB[64];
#pragma unroll
  for (int i = 0; i < 64; ++i) bufA[i] = wc[i * 64];
  float c = 0.f;
#pragma unroll
  for (int ch = 0; ch < 8; ++ch) {
#pragma unroll
    for (int i = 0; i < 64; ++i)
      bufB[i] = wc[((2 * ch + 1) * 64 + i) * 64];
#pragma unroll
    for (int i = 0; i < 64; ++i)
      c = __builtin_fmaf(qs[w][2 * ch * 64 + i], bufA[i], c);
    if (ch < 7) {
#pragma unroll
      for (int i = 0; i < 64; ++i)
        bufA[i] = wc[((2 * ch + 2) * 64 + i) * 64];
    }
#pragma unroll
    for (int i = 0; i < 64; ++i)
      c = __builtin_fmaf(qs[w][(2 * ch + 1) * 64 + i], bufB[i], c);
  }
  const float x = c;
  float r;
  if (x >= 0.f) r = __fdiv_rn(1.f, __fadd_rn(1.f, expf(-x)));
  else { const float ex = expf(x); r = __fdiv_rn(ex, __fadd_rn(1.f, ex)); }
  rates[b * 64 + j] = r;

  // gate logits: gather x across the wave's 64 lanes via shfl (ascending dd)
  const int jj = j & 15;
  float l = 0.f;
  for (int dd = 0; dd < 64; ++dd) {
    const float xv = __shfl(x, dd, 64);
    l = __builtin_fmaf(xv, gk[dd * 16 + jj], l);
  }
  l = __fadd_rn(l, gbias[jj]);
  l = __fdiv_rn(l, temp[0]);
  float m = l;
  for (int off = 1; off < 16; off <<= 1) m = fmaxf(m, __shfl_xor(m, off, 16));
  const float p = expf(__fsub_rn(l, m));
  float s = p;
  for (int off = 1; off < 16; off <<= 1) s += __shfl_xor(s, off, 16);
  if (j < 16) gateo[b * 16 + j] = __fdiv_rn(p, s);
}

// ---------- K1: fused {expert split+transpose | poisson spikes} --------------
__global__ __launch_bounds__(256) void k_prep(
    const float* __restrict__ ex, u16* __restrict__ wsp, float* __restrict__ ext,
    const float* __restrict__ rates, u16* __restrict__ spk, u32 bk0, u32 bk1)
{
  if (blockIdx.x < 256) {
    const int e = blockIdx.x >> 4, hb = blockIdx.x & 15;
    const int tl = threadIdx.x & 63, tg = threadIdx.x >> 6;
    __shared__ float tile[64][65];
#pragma unroll
    for (int r = 0; r < 16; ++r) {
      const int d = r * 4 + tg;
      tile[d][tl] = ex[((size_t)e * 64 + d) * 1024 + hb * 64 + tl];
    }
    __syncthreads();
#pragma unroll
    for (int r = 0; r < 16; ++r) {
      const int hl = r * 4 + tg;
      const float wraw = tile[tl][hl];
      const float wv = wraw * 0.05f;                 // fold leak = DT/TAU
      const u16 hi = f2bf(wv);
      const u16 lo = f2bf(wv - bf2f(hi));
      const size_t o = ((size_t)e * 1024 + hb * 64 + hl) * 64 + tl;
      wsp[o] = hi;
      wsp[o + 1048576] = lo;
      ext[o] = wraw;                                 // raw f32, [E][H][D]
    }
  } else {
    const u32 g = (blockIdx.x - 256) * 256u + threadIdx.x;
#if JAX_PARTITIONABLE
    u32 o0, o1;
    tf2x32(bk0, bk1, 0u, g, &o0, &o1);
    const u32 bits = o0 ^ o1;
    const float r = rates[g & 16383u];
    const float u = __uint_as_float((bits >> 9) | 0x3f800000u) - 1.0f;
    spk[g] = (u < r) ? (u16)0x3F80 : (u16)0;
#else
    u32 o0, o1;
    tf2x32(bk0, bk1, g, g + 163840u, &o0, &o1);
    const float r = rates[g & 16383u];
    const float ua = __uint_as_float((o0 >> 9) | 0x3f800000u) - 1.0f;
    const float ub = __uint_as_float((o1 >> 9) | 0x3f800000u) - 1.0f;
    spk[g] = (ua < r) ? (u16)0x3F80 : (u16)0;
    spk[g + 163840u] = (ub < r) ? (u16)0x3F80 : (u16)0;
#endif
  }
}

// ---------- K2: approx LIF scan, MFMA + flags -------------------------------
// nt=2 (wave tile 16b x 32h): 8 named frags = 32 VGPR resident without
// pressure (R7's nt=4 pin collapsed: VGPR=76 < the 104+ needed -> reloads).
// 2048 blocks (8/CU) for TLP. Numerics bit-identical to R5-R7 chain.
// grid (16 hblk, 8 bblk, 16 e), 256 thr = 4 waves.
__global__ __launch_bounds__(256) void k_lif(
    const u16* __restrict__ spk, const u16* __restrict__ wsp,
    u8* __restrict__ cnt, u32* __restrict__ fcnt, u32* __restrict__ flist)
{
  const int hblk = blockIdx.x, bblk = blockIdx.y, e = blockIdx.z;
  const int tid = threadIdx.x;
  const int w = tid >> 6, lane = tid & 63;
  const int wb = w & 1, wh = w >> 1;
  const int lr = lane & 15, lg = lane >> 4;
  const int b0 = bblk * 32 + wb * 16;
  const int h0 = hblk * 64 + wh * 32;

  // B frags: wsp[s][e][h][d]; lane: n = lr (h), k = kc*32 + lg*8 + j
#define FRAG(NT, KC, S) (*(const bf16x8*)(wsp + \
    ((size_t)((S) * 16 + e) * 1024 + h0 + (NT) * 16 + lr) * 64 + (KC) * 32 + lg * 8))
  bf16x8 bh00 = FRAG(0, 0, 0), bh01 = FRAG(0, 1, 0);
  bf16x8 bh10 = FRAG(1, 0, 0), bh11 = FRAG(1, 1, 0);
  bf16x8 bl00 = FRAG(0, 0, 1), bl01 = FRAG(0, 1, 1);
  bf16x8 bl10 = FRAG(1, 0, 1), bl11 = FRAG(1, 1, 1);
#undef FRAG
  asm volatile("" : "+v"(bh00), "+v"(bh01), "+v"(bh10), "+v"(bh11));
  asm volatile("" : "+v"(bl00), "+v"(bl01), "+v"(bl10), "+v"(bl11));

  f32x4 v0 = (f32x4){0.f, 0.f, 0.f, 0.f};
  f32x4 v1 = (f32x4){0.f, 0.f, 0.f, 0.f};
  int cn[2][4];
#pragma unroll
  for (int nt = 0; nt < 2; ++nt)
#pragma unroll
    for (int i = 0; i < 4; ++i) cn[nt][i] = 0;
  u32 fl = 0;

  const u16* abase = spk + (size_t)(b0 + lr) * 64 + lg * 8;
  bf16x8 a0 = *(const bf16x8*)(abase);
  bf16x8 a1 = *(const bf16x8*)(abase + 32);

#define PROC(VAL, CREF, BIT) {                                  \
    const float tt = (VAL) - 0.5f;                              \
    if (__builtin_fabsf(tt) < FLAG_DELTA) fl |= (1u << (BIT));  \
    const bool sp = (tt >= 0.f);                                \
    (CREF) += sp;                                               \
    (VAL) = sp ? 0.f : (VAL); }

  for (int t = 0; t < 20; ++t) {
    const int tn = (t < 19) ? t + 1 : 19;          // prefetch next (clamped)
    const bf16x8 n0 = *(const bf16x8*)(abase + (size_t)tn * 16384);
    const bf16x8 n1 = *(const bf16x8*)(abase + (size_t)tn * 16384 + 32);
    // nt = 0
    {
      f32x4 accA = v0 * 0.95f;
      accA = __builtin_amdgcn_mfma_f32_16x16x32_bf16(a0, bh00, accA, 0, 0, 0);
      accA = __builtin_amdgcn_mfma_f32_16x16x32_bf16(a1, bh01, accA, 0, 0, 0);
      f32x4 accB = (f32x4){0.f, 0.f, 0.f, 0.f};
      accB = __builtin_amdgcn_mfma_f32_16x16x32_bf16(a0, bl00, accB, 0, 0, 0);
      accB = __builtin_amdgcn_mfma_f32_16x16x32_bf16(a1, bl01, accB, 0, 0, 0);
      f32x4 nv = accA + accB;
      PROC(nv.x, cn[0][0], 0)
      PROC(nv.y, cn[0][1], 1)
      PROC(nv.z, cn[0][2], 2)
      PROC(nv.w, cn[0][3], 3)
      v0 = nv;
    }
    // nt = 1
    {
      f32x4 accA = v1 * 0.95f;
      accA = __builtin_amdgcn_mfma_f32_16x16x32_bf16(a0, bh10, accA, 0, 0, 0);
      accA = __builtin_amdgcn_mfma_f32_16x16x32_bf16(a1, bh11, accA, 0, 0, 0);
      f32x4 accB = (f32x4){0.f, 0.f, 0.f, 0.f};
      accB = __builtin_amdgcn_mfma_f32_16x16x32_bf16(a0, bl10, accB, 0, 0, 0);
      accB = __builtin_amdgcn_mfma_f32_16x16x32_bf16(a1, bl11, accB, 0, 0, 0);
      f32x4 nv = accA + accB;
      PROC(nv.x, cn[1][0], 4)
      PROC(nv.y, cn[1][1], 5)
      PROC(nv.z, cn[1][2], 6)
      PROC(nv.w, cn[1][3], 7)
      v1 = nv;
    }
    a0 = n0; a1 = n1;
  }
#undef PROC

  // C/D layout: col = lane&15 (h), row = (lane>>4)*4 + reg (b)
#pragma unroll
  for (int nt = 0; nt < 2; ++nt) {
    const int h = h0 + nt * 16 + lr;
#pragma unroll
    for (int i = 0; i < 4; ++i) {
      const int b = b0 + lg * 4 + i;
      cnt[((size_t)e * 256 + b) * 1024 + h] = (u8)cn[nt][i];
    }
  }

  // wave-aggregated flag append: <=1 atomic per wave
  const u32 myc = (u32)__builtin_popcount((int)fl);
  u32 pre = myc;
#pragma unroll
  for (int off = 1; off < 64; off <<= 1) {
    const u32 xx = __shfl_up(pre, off, 64);
    if (lane >= off) pre += xx;
  }
  const u32 tot = __shfl(pre, 63, 64);
  if (tot) {
    u32 base = 0;
    if (lane == 63) base = atomicAdd(fcnt, tot);
    base = __shfl(base, 63, 64);
    u32 slot = base + pre - myc;
    if (fl) {
#pragma unroll
      for (int nt = 0; nt < 2; ++nt)
#pragma unroll
        for (int i = 0; i < 4; ++i)
          if ((fl >> (nt * 4 + i)) & 1u) {
            if (slot < FLAG_CAP)
              flist[slot] = ((u32)e << 18) | ((u32)(b0 + lg * 4 + i) << 10) |
                            (u32)(h0 + nt * 16 + lr);
            slot++;
          }
    }
  }
}

// ---------- K2b: exact recompute of flagged elements (round-2 math) ---------
__global__ __launch_bounds__(256) void k_fix(
    const u16* __restrict__ spk, const float* __restrict__ ext,
    const u32* __restrict__ fcnt, const u32* __restrict__ flist,
    u8* __restrict__ cnt)
{
  u32 n = fcnt[0];
  if (n > FLAG_CAP) n = FLAG_CAP;
  for (u32 i = blockIdx.x * 256u + threadIdx.x; i < n; i += 65536u) {
    const u32 p = flist[i];
    const int h = (int)(p & 1023u), b = (int)((p >> 10) & 255u), e = (int)(p >> 18);
    const float* __restrict__ wbp = ext + ((size_t)e * 1024 + h) * 64;
    float wr[64];
#pragma unroll
    for (int d4 = 0; d4 < 16; ++d4) {
      const float4 wv = *(const float4*)(wbp + d4 * 4);
      wr[d4 * 4 + 0] = wv.x; wr[d4 * 4 + 1] = wv.y;
      wr[d4 * 4 + 2] = wv.z; wr[d4 * 4 + 3] = wv.w;
    }
    float v = 0.f;
    int c = 0;
    for (int t = 0; t < 20; ++t) {
      const uint4* __restrict__ sr = (const uint4*)(spk + (size_t)(t * 256 + b) * 64);
      float cc = 0.f;
#pragma unroll
      for (int w8 = 0; w8 < 8; ++w8) {
        const uint4 sv = sr[w8];
        cc = __builtin_fmaf(__uint_as_float(sv.x << 16),         wr[w8 * 8 + 0], cc);
        cc = __builtin_fmaf(__uint_as_float(sv.x & 0xFFFF0000u), wr[w8 * 8 + 1], cc);
        cc = __builtin_fmaf(__uint_as_float(sv.y << 16),         wr[w8 * 8 + 2], cc);
        cc = __builtin_fmaf(__uint_as_float(sv.y & 0xFFFF0000u), wr[w8 * 8 + 3], cc);
        cc = __builtin_fmaf(__uint_as_float(sv.z << 16),         wr[w8 * 8 + 4], cc);
        cc = __builtin_fmaf(__uint_as_float(sv.z & 0xFFFF0000u), wr[w8 * 8 + 5], cc);
        cc = __builtin_fmaf(__uint_as_float(sv.w << 16),         wr[w8 * 8 + 6], cc);
        cc = __builtin_fmaf(__uint_as_float(sv.w & 0xFFFF0000u), wr[w8 * 8 + 7], cc);
      }
      const float nv = __fadd_rn(v, __fmul_rn(__fsub_rn(cc, v), 0.05f));
      if (nv >= 0.5f) { c++; v = 0.f; } else v = nv;
    }
    cnt[((size_t)e * 256 + b) * 1024 + h] = (u8)c;
  }
}

// ---------- K3: out[b,h] = ascending-e fma chain of (cnt/20)*p --------------
// thread handles 4 consecutive h via uchar4 loads + float4 store.
__global__ __launch_bounds__(256) void k_combine(
    const u8* __restrict__ cnt, const float* __restrict__ gateo,
    float* __restrict__ out)
{
  const int idx = blockIdx.x * 256 + threadIdx.x;   // [0, 65536)
  const int b = idx >> 8, hq = idx & 255;
  const int h0 = hq * 4;
  float s0 = 0.f, s1 = 0.f, s2 = 0.f, s3 = 0.f;
#pragma unroll
  for (int e = 0; e < 16; ++e) {
    const uchar4 cv = *(const uchar4*)(cnt + ((size_t)e * 256 + b) * 1024 + h0);
    const float g = gateo[b * 16 + e];
    s0 = __builtin_fmaf(__fdiv_rn((float)cv.x, 20.f), g, s0);
    s1 = __builtin_fmaf(__fdiv_rn((float)cv.y, 20.f), g, s1);
    s2 = __builtin_fmaf(__fdiv_rn((float)cv.z, 20.f), g, s2);
    s3 = __builtin_fmaf(__fdiv_rn((float)cv.w, 20.f), g, s3);
  }
  float4 o;
  o.x = s0; o.y = s1; o.z = s2; o.w = s3;
  *(float4*)(out + (size_t)b * 1024 + h0) = o;
}

// ---------- launch ----------------------------------------------------------
extern "C" void kernel_launch(void* const* d_in, const int* in_sizes, int n_in,
                              void* d_out, int out_size, void* d_ws, size_t ws_size,
                              hipStream_t stream)
{
  (void)in_sizes; (void)n_in; (void)out_size; (void)ws_size;
  const float* q     = (const float*)d_in[0];
  const float* gbias = (const float*)d_in[1];
  const float* temp  = (const float*)d_in[2];
  const float* win   = (const float*)d_in[3];
  const float* ex    = (const float*)d_in[4];
  const float* gk    = (const float*)d_in[5];
  float* out = (float*)d_out;

  char* ws = (char*)d_ws;
  u16*  spk   = (u16*)(ws + 0);            // [20][256][64] bf16    655360 B
  float* rates = (float*)(ws + 655360);    // [256][64] f32          65536 B
  float* gateo = (float*)(ws + 720896);    // [256][16] f32          16384 B
  u16*  wsp   = (u16*)(ws + 737280);       // [2][16][1024][64]    4194304 B
  u8*   cnt   = (u8*)(ws + 4931584);       // [16][256][1024] u8   4194304 B
  u32*  fcnt  = (u32*)(ws + 9125888);      // counter                  4 B
  u32*  flist = (u32*)(ws + 9126912);      // [262144] u32         1048576 B
  float* ext  = (float*)(ws + 10175488);   // [16][1024][64] f32   4194304 B
                                           // total: 14369792 B

  u32 bk0, bk1;
#if JAX_PARTITIONABLE
  tf2x32(0u, 0u, 0u, 1u, &bk0, &bk1);
#else
  u32 a0o, a1o, b0o, b1o;
  tf2x32(0u, 0u, 0u, 2u, &a0o, &a1o);
  tf2x32(0u, 0u, 1u, 3u, &b0o, &b1o);
  bk0 = a1o; bk1 = b1o;
#endif

  k_gate<<<64, 256, 0, stream>>>(q, win, gbias, temp, gk, rates, gateo, fcnt);
#if JAX_PARTITIONABLE
  k_prep<<<256 + 1280, 256, 0, stream>>>(ex, wsp, ext, rates, spk, bk0, bk1);
#else
  k_prep<<<256 + 640, 256, 0, stream>>>(ex, wsp, ext, rates, spk, bk0, bk1);
#endif
  k_lif<<<dim3(16, 8, 16), 256, 0, stream>>>(spk, wsp, cnt, fcnt, flist);
  k_fix<<<256, 256, 0, stream>>>(spk, ext, fcnt, flist, cnt);
  k_combine<<<256, 256, 0, stream>>>(cnt, gateo, out);
}